// Round 1
// baseline (62.847 us; speedup 1.0000x reference)
//
#include <hip/hip_runtime.h>
#include <math.h>

// Problem constants (fixed by reference setup_inputs)
constexpr int B   = 128;
constexpr int T   = 300;
constexpr int D   = 1024;   // video dim
constexpr int DA  = 128;    // audio dim
constexpr int TS  = T - 1;  // 299 similarities per batch
constexpr int K   = 32;
constexpr int KP1 = K + 1;

constexpr int SEG = 16;                       // sims per wave
constexpr int WPB = (TS + SEG - 1) / SEG;     // 19 wave-segments per batch

#define EPS_D 1e-5

__device__ __forceinline__ void loadrow(const float* __restrict__ row, int lane, float r[16]) {
    const float4* f = (const float4*)row;
#pragma unroll
    for (int j = 0; j < 4; ++j) {
        float4 x = f[lane + 64 * j];
        r[4 * j + 0] = x.x; r[4 * j + 1] = x.y;
        r[4 * j + 2] = x.z; r[4 * j + 3] = x.w;
    }
}

// Kernel 1: adjacent-frame |cosine| similarities.
// One wave handles SEG consecutive sims for one batch; previous frame kept in
// registers so each video row is loaded ~once. Double accumulation + butterfly
// reduce for ordering-grade accuracy.
__global__ __launch_bounds__(256) void sims_kernel(const float* __restrict__ video,
                                                   float* __restrict__ sims) {
    int gid  = blockIdx.x * 256 + threadIdx.x;
    int wid  = gid >> 6;
    int lane = threadIdx.x & 63;
    int b    = wid / WPB;
    int seg  = wid % WPB;
    if (b >= B) return;

    int s0   = seg * SEG;
    int sEnd = min(s0 + SEG, TS);

    const float* vb = video + (size_t)b * T * D;

    float p[16];
    loadrow(vb + (size_t)s0 * D, lane, p);

    double pn = 0.0;
#pragma unroll
    for (int i = 0; i < 16; ++i) pn += (double)p[i] * (double)p[i];
#pragma unroll
    for (int o = 32; o; o >>= 1) pn += __shfl_xor(pn, o);

    for (int s = s0; s < sEnd; ++s) {
        float c[16];
        loadrow(vb + (size_t)(s + 1) * D, lane, c);

        double cn = 0.0, dt = 0.0;
#pragma unroll
        for (int i = 0; i < 16; ++i) {
            cn += (double)c[i] * (double)c[i];
            dt += (double)c[i] * (double)p[i];
        }
#pragma unroll
        for (int o = 32; o; o >>= 1) {
            cn += __shfl_xor(cn, o);
            dt += __shfl_xor(dt, o);
        }
        if (lane == 0) {
            double denom = (sqrt(pn) + EPS_D) * (sqrt(cn) + EPS_D);
            sims[b * TS + s] = (float)(fabs(dt) / denom);
        }
        pn = cn;
#pragma unroll
        for (int i = 0; i < 16; ++i) p[i] = c[i];
    }
}

// Kernel 2: per-batch stable top-K (smallest sim, tie -> smaller index),
// emitted in ascending-sim order. One wave per batch.
__global__ __launch_bounds__(64) void select_kernel(const float* __restrict__ sims,
                                                    int* __restrict__ idxOut) {
    int b    = blockIdx.x;
    int lane = threadIdx.x;
    const float INF = __int_as_float(0x7f800000);

    float v[5];
#pragma unroll
    for (int j = 0; j < 5; ++j) {
        int s = lane + 64 * j;
        v[j] = (s < TS) ? sims[b * TS + s] : INF;
    }

    for (int k = 0; k < K; ++k) {
        float lv = INF;
        int   li = 0x7fffffff;
        // local argmin; j ascending => s ascending, strict < keeps smallest s on tie
#pragma unroll
        for (int j = 0; j < 5; ++j) {
            int s = lane + 64 * j;
            if (v[j] < lv) { lv = v[j]; li = s; }
        }
        // wave argmin with index tie-break
#pragma unroll
        for (int o = 32; o; o >>= 1) {
            float ov = __shfl_xor(lv, o);
            int   oi = __shfl_xor(li, o);
            if (ov < lv || (ov == lv && oi < li)) { lv = ov; li = oi; }
        }
        if (lane == 0) idxOut[b * KP1 + 1 + k] = li + 1;
        // mark winner used (compile-time-constant register indexing)
        if ((li & 63) == lane) {
            int jw = li >> 6;
#pragma unroll
            for (int j = 0; j < 5; ++j)
                if (j == jw) v[j] = INF;
        }
    }
    if (lane == 0) idxOut[b * KP1] = 0;
}

// Kernel 3: gather selected rows of video + audio into concatenated output.
// Block (k, b) copies one video row (256 x float4) and one audio row (32 x float4).
__global__ __launch_bounds__(256) void gather_kernel(const float* __restrict__ video,
                                                     const float* __restrict__ audio,
                                                     const int* __restrict__ idx,
                                                     float* __restrict__ out) {
    int k = blockIdx.x;   // 0..32
    int b = blockIdx.y;   // 0..127
    int t = idx[b * KP1 + k];
    int tid = threadIdx.x;

    const float4* vs = (const float4*)(video + ((size_t)b * T + t) * D);
    float4*       vd = (float4*)(out + ((size_t)b * KP1 + k) * D);
    vd[tid] = vs[tid];

    if (tid < DA / 4) {
        const float4* as = (const float4*)(audio + ((size_t)b * T + t) * DA);
        float4*       ad = (float4*)(out + (size_t)B * KP1 * D + ((size_t)b * KP1 + k) * DA);
        ad[tid] = as[tid];
    }
}

extern "C" void kernel_launch(void* const* d_in, const int* in_sizes, int n_in,
                              void* d_out, int out_size, void* d_ws, size_t ws_size,
                              hipStream_t stream) {
    const float* video = (const float*)d_in[0];
    const float* audio = (const float*)d_in[1];
    float* out = (float*)d_out;

    float* sims = (float*)d_ws;
    int*   idx  = (int*)((char*)d_ws + (size_t)B * TS * sizeof(float));

    int nWaves  = B * WPB;                 // 2432
    int nBlocks = (nWaves * 64 + 255) / 256; // 608

    sims_kernel<<<nBlocks, 256, 0, stream>>>(video, sims);
    select_kernel<<<B, 64, 0, stream>>>(sims, idx);
    gather_kernel<<<dim3(KP1, B), 256, 0, stream>>>(video, audio, idx, out);
}